// Round 12
// baseline (209.739 us; speedup 1.0000x reference)
//
#include <hip/hip_runtime.h>
#include <cstdint>
#include <cstddef>

typedef float f32x16 __attribute__((ext_vector_type(16)));
typedef int i32x4 __attribute__((ext_vector_type(4)));
typedef int i32x8 __attribute__((ext_vector_type(8)));

#define FP8_MAX 448.0f

// async global->LDS, 16B per lane; LDS dest is wave-uniform base + lane*16
#define GL(gp, lp)                                               \
  __builtin_amdgcn_global_load_lds(                              \
      (const __attribute__((address_space(1))) void*)(gp),       \
      (__attribute__((address_space(3))) void*)(lp), 16, 0, 0)

__device__ __forceinline__ uint32_t pack4_e4m3(float a, float b, float c, float d) {
  int p = __builtin_amdgcn_cvt_pk_fp8_f32(a, b, 0, false);
  p = __builtin_amdgcn_cvt_pk_fp8_f32(c, d, p, true);
  return (uint32_t)p;
}

// Fused rowwise quant. Blocks [0,M): input rows -> row-major QA.
// Blocks [M,M+N): weight rows -> MFMA-FRAGMENT-ORDERED QWT (R7-proven):
//   k-byte k of col n -> QWT[(k>>6)*N*64 + (n>>5)*2048 + ((k>>5)&1)*1024
//                            + (n&31)*32 + (k&31)]
// so a wave's 32x32x64 B-fragment is 2 KiB contiguous, lane l at l*32.
__global__ __launch_bounds__(256) void quant_rowwise(
    const float* __restrict__ X, const float* __restrict__ W,
    uint8_t* __restrict__ QA, uint8_t* __restrict__ QWT,
    float* __restrict__ xsc, float* __restrict__ wsc, int K, int M, int N) {
  const int row = blockIdx.x;
  const bool is_w = row >= M;
  const int r = is_w ? row - M : row;
  const float* src = (is_w ? W : X) + (size_t)r * K;
  float* rec = (is_w ? wsc : xsc) + r;

  const int tid = threadIdx.x;
  const float4* __restrict__ x4 = (const float4*)src;
  float4 v[4];
  float am = 0.0f;
#pragma unroll
  for (int i = 0; i < 4; ++i) {
    v[i] = x4[i * 256 + tid];
    am = fmaxf(am, fmaxf(fmaxf(fabsf(v[i].x), fabsf(v[i].y)),
                         fmaxf(fabsf(v[i].z), fabsf(v[i].w))));
  }
#pragma unroll
  for (int off = 32; off > 0; off >>= 1)
    am = fmaxf(am, __shfl_xor(am, off));
  __shared__ float smax[4];
  const int wave = tid >> 6, lane = tid & 63;
  if (lane == 0) smax[wave] = am;
  __syncthreads();
  am = fmaxf(fmaxf(smax[0], smax[1]), fmaxf(smax[2], smax[3]));
  am = fmaxf(am, 1e-12f);
  const float scale = FP8_MAX / am;  // exact IEEE div (no fast-math)
  if (tid == 0) rec[0] = 1.0f / scale;

#pragma unroll
  for (int i = 0; i < 4; ++i) {
    float a = fminf(fmaxf(v[i].x * scale, -FP8_MAX), FP8_MAX);
    float b = fminf(fmaxf(v[i].y * scale, -FP8_MAX), FP8_MAX);
    float c = fminf(fmaxf(v[i].z * scale, -FP8_MAX), FP8_MAX);
    float d = fminf(fmaxf(v[i].w * scale, -FP8_MAX), FP8_MAX);
    const uint32_t p = pack4_e4m3(a, b, c, d);
    if (!is_w) {
      ((uint32_t*)(QA + (size_t)r * K))[i * 256 + tid] = p;
    } else {
      ((uint32_t*)QWT)[(size_t)(i * 16 + (tid >> 4)) * (N * 16) +
                       (size_t)(r >> 5) * 512 + ((tid >> 3) & 1) * 256 +
                       (r & 31) * 8 + (tid & 7)] = p;
    }
  }
}

// ---------------------------------------------------------------------------
// MX-scaled fp8 GEMM (all E8M0 scales = 1.0 == exact fp8 e4m3 matmul).
// R5's hardware-proven schedule (iter-top COUNTED gate + 1 barrier, loads
// issued mid-iter, NEVER a drain of fresh ops, no mid-iter waits) with
// B taken out of LDS:
//  - A in LDS: 3 x 16 KiB triple buffer, distance-2 DMA prefetch, chunk
//    swizzle stored[r][c]=logical[r][c^((r>>1)&3)] both-sides (rule #21).
//    Per-iter LDS = 64 KiB read + 16 KiB DMA write (~900 cy) < MFMA 1100 cy.
//  - B DIRECT from fragment-ordered QWT (2 KiB coalesced per frag, L1/L2-
//    served), ping-pong reg sets; B(t+1) issued at iter t, consumed at t+1.
// ORDER-SAFE counted ledger (the R9/R10 lesson): per iter the two issue
// groups are separated by sched_barrier(0):  [B(t+1) x4] || [A-GL(t+2) x2].
// Queue at top of iter t+1 (oldest->newest):
//   [A(t+1)x2, B(t+1)x4, A(t+2)x2]  ->  vmcnt(2) retires exactly A(t+1)
// (LDS publish, pre-barrier) + B(t+1) (this iter's MFMA operand) and leaves
// A(t+2) in flight. Prologue [A(0)x2, B(0)x4, A(1)x2] matches the invariant.
// sched_barrier(0) after s_barrier: ds_reads can't hoist above the barrier.
// 256x256 tile, 8 waves (2M x 4N); per-wave 128x64 = acc[4][2] f32x16.
// A frag: lane l: row=l&31, k-bytes 32*(l>>5)+0..31. C/D 32x32: col=l&31,
// row=(reg&3)+8*(reg>>2)+4*(l>>5) [m74/m101, dtype-independent].
// ---------------------------------------------------------------------------

#define MMS(TM, TN, A, B)                                          \
  acc[TM][TN] = __builtin_amdgcn_mfma_scale_f32_32x32x64_f8f6f4(   \
      (A), (B), acc[TM][TN], 0, 0, 0, 0x7F7F7F7F, 0, 0x7F7F7F7F);

// stage A K-tile kt (256 rows x 64 B) into A-slot BI (2 GL, 16 rows each)
#define STAGEA(KT, BI)                                                     \
  do {                                                                     \
    GL(Aq + aoff + (size_t)(KT) * 64, &lds[(BI) * 16384 + w * 2048]);      \
    GL(Aq + aoff2 + (size_t)(KT) * 64,                                     \
       &lds[(BI) * 16384 + w * 2048 + 1024]);                              \
  } while (0)

// direct coalesced B frags (tn=0,1) for K-tile TT (4x global dwordx4)
#define LOADB(B0, B1, TT)                                                  \
  do {                                                                     \
    const uint8_t* bp = BqT + (size_t)(TT) * nstride + bgrp;               \
    i32x4 l0 = *(const i32x4*)(bp);                                        \
    i32x4 h0 = *(const i32x4*)(bp + 16);                                   \
    i32x4 l1 = *(const i32x4*)(bp + 2048);                                 \
    i32x4 h1 = *(const i32x4*)(bp + 2064);                                 \
    B0 = __builtin_shufflevector(l0, h0, 0, 1, 2, 3, 4, 5, 6, 7);          \
    B1 = __builtin_shufflevector(l1, h1, 0, 1, 2, 3, 4, 5, 6, 7);          \
  } while (0)

__device__ __forceinline__ i32x8 ldfrag(const uint8_t* p, int off) {
  i32x4 lo = *(const i32x4*)(p + off);         // logical k-bytes 0-15
  i32x4 hi = *(const i32x4*)(p + (off ^ 16));  // logical k-bytes 16-31
  return __builtin_shufflevector(lo, hi, 0, 1, 2, 3, 4, 5, 6, 7);
}

// Consume B-set C (loaded last iter); load B-set N for t+1; MFMA tile T.
#define ITER(BC0, BC1, BN0, BN1, T)                                        \
  do {                                                                     \
    asm volatile("s_waitcnt vmcnt(2)" ::: "memory");                       \
    __builtin_amdgcn_s_barrier();                                          \
    __builtin_amdgcn_sched_barrier(0);                                     \
    const int t1_ = ((T) + 1 < nk) ? (T) + 1 : (T);                        \
    const int pf_ = ((T) + 2 < nk) ? (T) + 2 : (T);                        \
    const int sA_ = ((T) % 3) * 16384 + arow;                              \
    i32x8 a0 = ldfrag(lds, sA_);                                           \
    i32x8 a1 = ldfrag(lds, sA_ + 2048);                                    \
    i32x8 a2 = ldfrag(lds, sA_ + 4096);                                    \
    i32x8 a3 = ldfrag(lds, sA_ + 6144);                                    \
    LOADB(BN0, BN1, t1_);                                                  \
    __builtin_amdgcn_sched_barrier(0);  /* B-loads before A-GLs (ledger) */ \
    STAGEA(pf_, ((T) + 2) % 3);                                            \
    __builtin_amdgcn_s_setprio(1);                                         \
    MMS(0, 0, a0, BC0) MMS(0, 1, a0, BC1)                                  \
    MMS(1, 0, a1, BC0) MMS(1, 1, a1, BC1)                                  \
    MMS(2, 0, a2, BC0) MMS(2, 1, a2, BC1)                                  \
    MMS(3, 0, a3, BC0) MMS(3, 1, a3, BC1)                                  \
    __builtin_amdgcn_s_setprio(0);                                         \
  } while (0)

__global__ __launch_bounds__(512, 1) void gemm_fp8(
    const uint8_t* __restrict__ Aq, const uint8_t* __restrict__ BqT,
    const float* __restrict__ xs, const float* __restrict__ wsc,
    const float* __restrict__ bias, float* __restrict__ C,
    int M, int N, int K) {
  __shared__ __align__(16) uint8_t lds[49152];  // 3 x 16 KiB A buffers
  const int tid = threadIdx.x;
  const int w = tid >> 6, lane = tid & 63;
  const int wrow = w >> 2, wcol = w & 3;

  // XCD-aware bijective swizzle: 512 WGs, 8 XCDs, 64 per XCD.
  int bid = (int)blockIdx.x;
  bid = (bid & 7) * 64 + (bid >> 3);
  const int bm = bid & 31, bn = bid >> 5;
  const int row0 = bm * 256, col0 = bn * 256;

  const int ln31 = lane & 31;
  const size_t nstride = (size_t)N * 64;

  // A staging source (pre-swizzled logical chunk)
  const int srow = lane >> 2;
  const int scol = 16 * ((lane & 3) ^ ((lane >> 3) & 3));
  const size_t aoff = (size_t)(row0 + w * 32 + srow) * K + scol;
  const size_t aoff2 = aoff + (size_t)16 * K;

  // A ds_read base: row = wrow*128 + ln31 (+tm*32), chunk = logical^((r>>1)&3)
  const int g2 = (lane >> 5) * 2;
  const int o0 = 16 * (g2 ^ ((ln31 >> 1) & 3));
  const int arow = (wrow * 128 + ln31) * 64 + o0;

  // B direct-load base (fragment-ordered): wave's col-group, lane's 32 B
  const size_t bgrp = (size_t)((col0 + wcol * 64) >> 5) * 2048 + (size_t)lane * 32;

  f32x16 zero = {};
  f32x16 acc[4][2];
#pragma unroll
  for (int m = 0; m < 4; ++m)
#pragma unroll
    for (int n = 0; n < 2; ++n) acc[m][n] = zero;

  const int nk = K / 64;
  i32x8 bE0, bE1, bO0, bO1;

  // prologue queue (oldest->newest): [A(0)x2, B(0)x4, A(1)x2]
  STAGEA(0, 0);
  __builtin_amdgcn_sched_barrier(0);
  LOADB(bE0, bE1, 0);
  __builtin_amdgcn_sched_barrier(0);
  STAGEA(1, 1);

  for (int t = 0; t < nk; t += 2) {
    ITER(bE0, bE1, bO0, bO1, t);
    ITER(bO0, bO1, bE0, bE1, t + 1);
  }

  // epilogue: C/D 32x32 layout col=lane&31, row=(reg&3)+8*(reg>>2)+4*(lane>>5)
  const int cl = lane & 31;
  const int rtop = (lane >> 5) * 4;
#pragma unroll
  for (int tm = 0; tm < 4; ++tm) {
#pragma unroll
    for (int tn = 0; tn < 2; ++tn) {
      const int col = col0 + wcol * 64 + tn * 32 + cl;
      const float wsn = wsc[col];
      const float bb = bias[col];
      const int rowb = row0 + wrow * 128 + tm * 32 + rtop;
#pragma unroll
      for (int q = 0; q < 4; ++q) {
        const float4 xq = *(const float4*)&xs[rowb + 8 * q];
        const float xa[4] = {xq.x, xq.y, xq.z, xq.w};
#pragma unroll
        for (int j = 0; j < 4; ++j) {
          const int r = rowb + 8 * q + j;
          C[(size_t)r * N + col] = fmaf(acc[tm][tn][4 * q + j] * xa[j], wsn, bb);
        }
      }
    }
  }
}

extern "C" void kernel_launch(void* const* d_in, const int* in_sizes, int n_in,
                              void* d_out, int out_size, void* d_ws, size_t ws_size,
                              hipStream_t stream) {
  const float* input = (const float*)d_in[0];   // [M,K] fp32
  const float* weight = (const float*)d_in[1];  // [N,K] fp32
  const float* bias = (const float*)d_in[2];    // [N]   fp32
  float* out = (float*)d_out;                   // [M,N] fp32

  const int K = 4096;
  const int N = in_sizes[2];
  const int M = in_sizes[0] / K;

  uint8_t* qA = (uint8_t*)d_ws;                    // [M,K] row-major
  uint8_t* qWT = qA + (size_t)M * K;               // fragment-ordered
  float* xsc = (float*)(qWT + (size_t)N * K);
  float* wsc = xsc + M;

  quant_rowwise<<<M + N, 256, 0, stream>>>(input, weight, qA, qWT, xsc, wsc,
                                           K, M, N);

  dim3 grid((M / 256) * (N / 256));
  gemm_fp8<<<grid, 512, 0, stream>>>(qA, qWT, xsc, wsc, bias, out, M, N, K);
}

// Round 13
// 194.444 us; speedup vs baseline: 1.0787x; 1.0787x over previous
//
#include <hip/hip_runtime.h>
#include <cstdint>
#include <cstddef>

typedef float f32x16 __attribute__((ext_vector_type(16)));
typedef int i32x4 __attribute__((ext_vector_type(4)));
typedef int i32x8 __attribute__((ext_vector_type(8)));

#define FP8_MAX 448.0f

// async global->LDS, 16B per lane; LDS dest is wave-uniform base + lane*16
#define GL(gp, lp)                                               \
  __builtin_amdgcn_global_load_lds(                              \
      (const __attribute__((address_space(1))) void*)(gp),       \
      (__attribute__((address_space(3))) void*)(lp), 16, 0, 0)

__device__ __forceinline__ uint32_t pack4_e4m3(float a, float b, float c, float d) {
  int p = __builtin_amdgcn_cvt_pk_fp8_f32(a, b, 0, false);
  p = __builtin_amdgcn_cvt_pk_fp8_f32(c, d, p, true);
  return (uint32_t)p;
}

// Fused rowwise quant. Blocks [0,M): input rows -> row-major QA.
// Blocks [M,M+N): weight rows -> MFMA-FRAGMENT-ORDERED QWT (R7-proven):
//   k-byte k of col n -> QWT[(k>>6)*N*64 + (n>>5)*2048 + ((k>>5)&1)*1024
//                            + (n&31)*32 + (k&31)]
__global__ __launch_bounds__(256) void quant_rowwise(
    const float* __restrict__ X, const float* __restrict__ W,
    uint8_t* __restrict__ QA, uint8_t* __restrict__ QWT,
    float* __restrict__ xsc, float* __restrict__ wsc, int K, int M, int N) {
  const int row = blockIdx.x;
  const bool is_w = row >= M;
  const int r = is_w ? row - M : row;
  const float* src = (is_w ? W : X) + (size_t)r * K;
  float* rec = (is_w ? wsc : xsc) + r;

  const int tid = threadIdx.x;
  const float4* __restrict__ x4 = (const float4*)src;
  float4 v[4];
  float am = 0.0f;
#pragma unroll
  for (int i = 0; i < 4; ++i) {
    v[i] = x4[i * 256 + tid];
    am = fmaxf(am, fmaxf(fmaxf(fabsf(v[i].x), fabsf(v[i].y)),
                         fmaxf(fabsf(v[i].z), fabsf(v[i].w))));
  }
#pragma unroll
  for (int off = 32; off > 0; off >>= 1)
    am = fmaxf(am, __shfl_xor(am, off));
  __shared__ float smax[4];
  const int wave = tid >> 6, lane = tid & 63;
  if (lane == 0) smax[wave] = am;
  __syncthreads();
  am = fmaxf(fmaxf(smax[0], smax[1]), fmaxf(smax[2], smax[3]));
  am = fmaxf(am, 1e-12f);
  const float scale = FP8_MAX / am;  // exact IEEE div (no fast-math)
  if (tid == 0) rec[0] = 1.0f / scale;

#pragma unroll
  for (int i = 0; i < 4; ++i) {
    float a = fminf(fmaxf(v[i].x * scale, -FP8_MAX), FP8_MAX);
    float b = fminf(fmaxf(v[i].y * scale, -FP8_MAX), FP8_MAX);
    float c = fminf(fmaxf(v[i].z * scale, -FP8_MAX), FP8_MAX);
    float d = fminf(fmaxf(v[i].w * scale, -FP8_MAX), FP8_MAX);
    const uint32_t p = pack4_e4m3(a, b, c, d);
    if (!is_w) {
      ((uint32_t*)(QA + (size_t)r * K))[i * 256 + tid] = p;
    } else {
      ((uint32_t*)QWT)[(size_t)(i * 16 + (tid >> 4)) * (N * 16) +
                       (size_t)(r >> 5) * 512 + ((tid >> 3) & 1) * 256 +
                       (r & 31) * 8 + (tid & 7)] = p;
    }
  }
}

// ---------------------------------------------------------------------------
// MX-scaled fp8 GEMM (all E8M0 scales = 1.0 == exact fp8 e4m3 matmul).
// TLP structure: 128x256 tile, 4 waves (1M x 4N), 256 threads,
// __launch_bounds__(256,2) -> TWO independent blocks per CU. One block's
// read/barrier convoy overlaps the other block's MFMA phase via hardware
// wave scheduling (m114) -- no intra-block reordering needed.
//  - A in LDS: 3 x 8 KiB triple buffer, distance-2 DMA prefetch, chunk
//    swizzle stored[r][c]=logical[r][c^((r>>1)&3)] both-sides (rule #21).
//  - B DIRECT from fragment-ordered QWT (2 KiB coalesced per frag),
//    ping-pong reg sets; B(t+1) issued at iter t, consumed at t+1.
// Per-CU (2 blocks) LDS/iter-pair = 2x(32 read + 8 DMA) = 80 KiB (~960 cy)
// < MFMA 1100 cy -> MFMA is the pole (59 us floor).
// ORDER-SAFE fenced ledger (R12 hardware-validated): per iter issue groups
// [B(t+1)x4] || sched_barrier || [A-GL(t+2)x2]; queue at iter top =
// [A(t+1)x2, B(t+1)x4, A(t+2)x2] -> vmcnt(2) retires exactly what's needed,
// never drains fresh ops. sched_barrier(0) after s_barrier (no hoisting).
// Per-wave 128x64 = acc[4][2] f32x16; every wave reads all 128 A rows
// (frag tm at +tm*2048 within the 8 KiB slot; swizzle tm-invariant since
// (tm*32)>>1 mod 4 == 0).
// A frag: lane l: row=l&31, k-bytes 32*(l>>5)+0..31. C/D 32x32: col=l&31,
// row=(reg&3)+8*(reg>>2)+4*(l>>5) [m74/m101, dtype-independent].
// ---------------------------------------------------------------------------

#define MMS(TM, TN, A, B)                                          \
  acc[TM][TN] = __builtin_amdgcn_mfma_scale_f32_32x32x64_f8f6f4(   \
      (A), (B), acc[TM][TN], 0, 0, 0, 0x7F7F7F7F, 0, 0x7F7F7F7F);

// stage A K-tile kt (128 rows x 64 B = 8 KiB) into A-slot BI (2 GL/wave,
// wave w covers rows [w*32, w*32+32))
#define STAGEA(KT, BI)                                                     \
  do {                                                                     \
    GL(Aq + aoff + (size_t)(KT) * 64, &lds[(BI) * 8192 + w * 2048]);       \
    GL(Aq + aoff2 + (size_t)(KT) * 64,                                     \
       &lds[(BI) * 8192 + w * 2048 + 1024]);                               \
  } while (0)

// direct coalesced B frags (tn=0,1) for K-tile TT (4x global dwordx4)
#define LOADB(B0, B1, TT)                                                  \
  do {                                                                     \
    const uint8_t* bp = BqT + (size_t)(TT) * nstride + bgrp;               \
    i32x4 l0 = *(const i32x4*)(bp);                                        \
    i32x4 h0 = *(const i32x4*)(bp + 16);                                   \
    i32x4 l1 = *(const i32x4*)(bp + 2048);                                 \
    i32x4 h1 = *(const i32x4*)(bp + 2064);                                 \
    B0 = __builtin_shufflevector(l0, h0, 0, 1, 2, 3, 4, 5, 6, 7);          \
    B1 = __builtin_shufflevector(l1, h1, 0, 1, 2, 3, 4, 5, 6, 7);          \
  } while (0)

__device__ __forceinline__ i32x8 ldfrag(const uint8_t* p, int off) {
  i32x4 lo = *(const i32x4*)(p + off);         // logical k-bytes 0-15
  i32x4 hi = *(const i32x4*)(p + (off ^ 16));  // logical k-bytes 16-31
  return __builtin_shufflevector(lo, hi, 0, 1, 2, 3, 4, 5, 6, 7);
}

// Consume B-set C (loaded last iter); load B-set N for t+1; MFMA tile T.
#define ITER(BC0, BC1, BN0, BN1, T)                                        \
  do {                                                                     \
    asm volatile("s_waitcnt vmcnt(2)" ::: "memory");                       \
    __builtin_amdgcn_s_barrier();                                          \
    __builtin_amdgcn_sched_barrier(0);                                     \
    const int t1_ = ((T) + 1 < nk) ? (T) + 1 : (T);                        \
    const int pf_ = ((T) + 2 < nk) ? (T) + 2 : (T);                        \
    const int sA_ = ((T) % 3) * 8192 + arow;                               \
    i32x8 a0 = ldfrag(lds, sA_);                                           \
    i32x8 a1 = ldfrag(lds, sA_ + 2048);                                    \
    i32x8 a2 = ldfrag(lds, sA_ + 4096);                                    \
    i32x8 a3 = ldfrag(lds, sA_ + 6144);                                    \
    LOADB(BN0, BN1, t1_);                                                  \
    __builtin_amdgcn_sched_barrier(0);  /* B-loads before A-GLs (ledger) */ \
    STAGEA(pf_, ((T) + 2) % 3);                                            \
    __builtin_amdgcn_s_setprio(1);                                         \
    MMS(0, 0, a0, BC0) MMS(0, 1, a0, BC1)                                  \
    MMS(1, 0, a1, BC0) MMS(1, 1, a1, BC1)                                  \
    MMS(2, 0, a2, BC0) MMS(2, 1, a2, BC1)                                  \
    MMS(3, 0, a3, BC0) MMS(3, 1, a3, BC1)                                  \
    __builtin_amdgcn_s_setprio(0);                                         \
  } while (0)

__global__ __launch_bounds__(256, 2) void gemm_fp8(
    const uint8_t* __restrict__ Aq, const uint8_t* __restrict__ BqT,
    const float* __restrict__ xs, const float* __restrict__ wsc,
    const float* __restrict__ bias, float* __restrict__ C,
    int M, int N, int K) {
  __shared__ __align__(16) uint8_t lds[24576];  // 3 x 8 KiB A buffers
  const int tid = threadIdx.x;
  const int w = tid >> 6, lane = tid & 63;

  // XCD-aware bijective swizzle: 1024 WGs, 8 XCDs, 128 per XCD.
  // bm fast-varying within an XCD -> B panel (1 MB) L2-resident.
  int bid = (int)blockIdx.x;
  bid = (bid & 7) * 128 + (bid >> 3);
  const int bm = bid & 63, bn = bid >> 6;
  const int row0 = bm * 128, col0 = bn * 256;

  const int ln31 = lane & 31;
  const size_t nstride = (size_t)N * 64;

  // A staging source (pre-swizzled logical chunk); wave w rows [w*32,w*32+32)
  const int srow = lane >> 2;
  const int scol = 16 * ((lane & 3) ^ ((lane >> 3) & 3));
  const size_t aoff = (size_t)(row0 + w * 32 + srow) * K + scol;
  const size_t aoff2 = aoff + (size_t)16 * K;

  // A ds_read base: row = tm*32 + ln31, chunk = logical^((r>>1)&3)
  // ((tm*32)>>1 mod 4 == 0 -> swizzle term tm-invariant)
  const int g2 = (lane >> 5) * 2;
  const int o0 = 16 * (g2 ^ ((ln31 >> 1) & 3));
  const int arow = ln31 * 64 + o0;  // + tm*2048

  // B direct-load base (fragment-ordered): wave's col-group, lane's 32 B
  const size_t bgrp = (size_t)((col0 + w * 64) >> 5) * 2048 + (size_t)lane * 32;

  f32x16 zero = {};
  f32x16 acc[4][2];
#pragma unroll
  for (int m = 0; m < 4; ++m)
#pragma unroll
    for (int n = 0; n < 2; ++n) acc[m][n] = zero;

  const int nk = K / 64;
  i32x8 bE0, bE1, bO0, bO1;

  // prologue queue (oldest->newest): [A(0)x2, B(0)x4, A(1)x2]
  STAGEA(0, 0);
  __builtin_amdgcn_sched_barrier(0);
  LOADB(bE0, bE1, 0);
  __builtin_amdgcn_sched_barrier(0);
  STAGEA(1, 1);

  for (int t = 0; t < nk; t += 2) {
    ITER(bE0, bE1, bO0, bO1, t);
    ITER(bO0, bO1, bE0, bE1, t + 1);
  }

  // epilogue: C/D 32x32 layout col=lane&31, row=(reg&3)+8*(reg>>2)+4*(lane>>5)
  const int cl = lane & 31;
  const int rtop = (lane >> 5) * 4;
#pragma unroll
  for (int tm = 0; tm < 4; ++tm) {
#pragma unroll
    for (int tn = 0; tn < 2; ++tn) {
      const int col = col0 + w * 64 + tn * 32 + cl;
      const float wsn = wsc[col];
      const float bb = bias[col];
      const int rowb = row0 + tm * 32 + rtop;
#pragma unroll
      for (int q = 0; q < 4; ++q) {
        const float4 xq = *(const float4*)&xs[rowb + 8 * q];
        const float xa[4] = {xq.x, xq.y, xq.z, xq.w};
#pragma unroll
        for (int j = 0; j < 4; ++j) {
          const int r = rowb + 8 * q + j;
          C[(size_t)r * N + col] = fmaf(acc[tm][tn][4 * q + j] * xa[j], wsn, bb);
        }
      }
    }
  }
}

extern "C" void kernel_launch(void* const* d_in, const int* in_sizes, int n_in,
                              void* d_out, int out_size, void* d_ws, size_t ws_size,
                              hipStream_t stream) {
  const float* input = (const float*)d_in[0];   // [M,K] fp32
  const float* weight = (const float*)d_in[1];  // [N,K] fp32
  const float* bias = (const float*)d_in[2];    // [N]   fp32
  float* out = (float*)d_out;                   // [M,N] fp32

  const int K = 4096;
  const int N = in_sizes[2];
  const int M = in_sizes[0] / K;

  uint8_t* qA = (uint8_t*)d_ws;                    // [M,K] row-major
  uint8_t* qWT = qA + (size_t)M * K;               // fragment-ordered
  float* xsc = (float*)(qWT + (size_t)N * K);
  float* wsc = xsc + M;

  quant_rowwise<<<M + N, 256, 0, stream>>>(input, weight, qA, qWT, xsc, wsc,
                                           K, M, N);

  dim3 grid((M / 128) * (N / 256));
  gemm_fp8<<<grid, 256, 0, stream>>>(qA, qWT, xsc, wsc, bias, out, M, N, K);
}